// Round 3
// baseline (423.916 us; speedup 1.0000x reference)
//
#include <hip/hip_runtime.h>
#include <math.h>

#define B_ 32
#define L_ 8192
#define D_ 256
#define M_ 4097   // L/2 + 1

typedef float floatx4 __attribute__((ext_vector_type(4)));

// ---------------------------------------------------------------------------
// K1: s[b,l] = sigmoid(dot(x[b,l,:], W) + bias).  One wave per 4 rows: all 4
// float4 x-loads issued up front (4x MLP), then 4 independent xor-shuffle
// reductions.  Reduction tree is bitwise-identical to the R1 version so the
// valley mask cannot flip on rounding.
// ---------------------------------------------------------------------------
__global__ __launch_bounds__(256) void k_sigmoid_dot(
    const float* __restrict__ x, const float* __restrict__ W,
    const float* __restrict__ bias, float* __restrict__ s)
{
    int wave = threadIdx.x >> 6;
    int lane = threadIdx.x & 63;
    int row0 = blockIdx.x * 16 + wave * 4;

    const float4 wv = ((const float4*)W)[lane];
    float4 xv[4];
#pragma unroll
    for (int i = 0; i < 4; i++)
        xv[i] = ((const float4*)(x + (size_t)(row0 + i) * D_))[lane];
    float zb = bias[0];

#pragma unroll
    for (int i = 0; i < 4; i++) {
        float p = xv[i].x * wv.x + xv[i].y * wv.y + xv[i].z * wv.z + xv[i].w * wv.w;
#pragma unroll
        for (int off = 32; off > 0; off >>= 1)
            p += __shfl_xor(p, off, 64);
        if (lane == 0)
            s[row0 + i] = 1.0f / (1.0f + expf(-(p + zb)));
    }
}

// ---------------------------------------------------------------------------
// K2: per batch: strict-local-min mask (zero-padded neighbors, frame 0 forced
// true), block scan for prefix ranks, compact starts, emit counts.
// 256 threads/batch, each owns 32 frames; loads issued as 8 float4 + 2 halo
// scalars up front (independent), mask computed from registers.
// ---------------------------------------------------------------------------
__global__ __launch_bounds__(256) void k_scan(
    const float* __restrict__ s, int* __restrict__ starts,
    int* __restrict__ counts, float* __restrict__ out_counts)
{
    int b = blockIdx.x;
    const float* sb = s + (size_t)b * L_;
    int t    = threadIdx.x;
    int base = t * 32;

    float f[34];
    f[0]  = (t == 0)   ? 0.0f : sb[base - 1];
    f[33] = (t == 255) ? 0.0f : sb[base + 32];
#pragma unroll
    for (int i = 0; i < 8; i++) {
        float4 q = ((const float4*)(sb + base))[i];
        f[1 + 4 * i] = q.x; f[2 + 4 * i] = q.y;
        f[3 + 4 * i] = q.z; f[4 + 4 * i] = q.w;
    }

    unsigned bits = 0;
    int cnt = 0;
#pragma unroll
    for (int i = 0; i < 32; i++) {
        bool m = ((f[i + 1] < f[i]) && (f[i + 1] < f[i + 2])) || (base + i == 0);
        if (m) { bits |= (1u << i); cnt++; }
    }

    __shared__ int sh[256];
    sh[t] = cnt;
    __syncthreads();
    for (int off = 1; off < 256; off <<= 1) {     // Hillis-Steele inclusive
        int v = (t >= off) ? sh[t - off] : 0;
        __syncthreads();
        sh[t] += v;
        __syncthreads();
    }
    int excl  = sh[t] - cnt;
    int total = sh[255];

    int k = excl;
    for (int i = 0; i < 32; i++) {
        if (bits & (1u << i)) { starts[b * M_ + k] = base + i; k++; }
    }
    if (t == 0) {
        counts[b]     = total;
        out_counts[b] = (float)total;   // harness reads flat out buffer as f32
    }
}

// ---------------------------------------------------------------------------
// K3: 4 waves/block, 2 output rows per wave (independent unrolled chains).
// k >= count -> zero row (d_out poisoned each timed launch).  Nontemporal
// stores for the streaming 134 MB output; x loads stay cacheable (LLC reuse).
// ---------------------------------------------------------------------------
__device__ __forceinline__ void nt_store4(float* p, float4 v) {
    floatx4 nv = { v.x, v.y, v.z, v.w };
    __builtin_nontemporal_store(nv, (floatx4*)p);
}

__global__ __launch_bounds__(256) void k_write(
    const float* __restrict__ x, const float* __restrict__ s,
    const int* __restrict__ starts, const int* __restrict__ counts,
    float* __restrict__ out)
{
    int wave = threadIdx.x >> 6;
    int lane = threadIdx.x & 63;
    int b    = blockIdx.y;
    int k0   = (blockIdx.x * 4 + wave) * 2;
    int cnt  = counts[b];
    const float* sb = s + (size_t)b * L_;

#pragma unroll
    for (int j = 0; j < 2; j++) {
        int k = k0 + j;
        if (k >= M_) continue;
        float* orow = out + ((size_t)b * M_ + k) * D_ + lane * 4;
        if (k >= cnt) {
            nt_store4(orow, make_float4(0.f, 0.f, 0.f, 0.f));
            continue;
        }
        int p = starts[b * M_ + k];
        float s0 = sb[p];
        bool has1 = (p + 1 < L_);
        float s1 = has1 ? sb[p + 1] : 0.0f;
        float inv = 1.0f / fmaxf(s0 + s1, 1e-6f);

        const float4* x0 = (const float4*)(x + ((size_t)b * L_ + p) * D_);
        float4 a = x0[lane];
        float4 r;
        r.x = s0 * a.x; r.y = s0 * a.y; r.z = s0 * a.z; r.w = s0 * a.w;
        if (has1) {
            float4 c = (x0 + (D_ / 4))[lane];
            r.x += s1 * c.x; r.y += s1 * c.y; r.z += s1 * c.z; r.w += s1 * c.w;
        }
        r.x *= inv; r.y *= inv; r.z *= inv; r.w *= inv;
        nt_store4(orow, r);
    }
}

extern "C" void kernel_launch(void* const* d_in, const int* in_sizes, int n_in,
                              void* d_out, int out_size, void* d_ws, size_t ws_size,
                              hipStream_t stream) {
    const float* x    = (const float*)d_in[0];
    // d_in[1] = olens: unused by the reference
    const float* W    = (const float*)d_in[2];
    const float* bias = (const float*)d_in[3];

    float* out        = (float*)d_out;
    float* out_counts = out + (size_t)B_ * M_ * D_;   // counts tail, as f32

    float* s      = (float*)d_ws;                                   // B*L f32 (1 MB)
    int*   starts = (int*)((char*)d_ws + (size_t)B_ * L_ * 4);      // B*M i32
    int*   counts = (int*)((char*)starts + (size_t)B_ * M_ * 4);    // B   i32

    k_sigmoid_dot<<<(B_ * L_) / 16, 256, 0, stream>>>(x, W, bias, s);
    k_scan<<<B_, 256, 0, stream>>>(s, starts, counts, out_counts);
    k_write<<<dim3((M_ + 7) / 8, B_), 256, 0, stream>>>(x, s, starts, counts, out);
}